// Round 1
// baseline (441.506 us; speedup 1.0000x reference)
//
#include <hip/hip_runtime.h>
#include <stdint.h>

#define NN 8192
#define FD 256
#define LOG2E 1.44269504088896340736f
#define SPLIT 8
#define JSLICE (NN / SPLIT)      // 1024 j per gat block
#define NIT (JSLICE / 32)        // 32 iterations of 32 j (16 KB B-chunk each)

typedef __attribute__((ext_vector_type(8))) __bf16 bf16x8;
typedef __attribute__((ext_vector_type(4))) float f32x4;

__device__ __forceinline__ unsigned short f2bf(float x) {
    unsigned u = __float_as_uint(x);
    u = u + 0x7fffu + ((u >> 16) & 1u);   // RNE; no NaNs in this problem
    return (unsigned short)(u >> 16);
}
__device__ __forceinline__ bf16x8 ld_bf8(const unsigned short* p) {
    uint4 v = *(const uint4*)p;
    return __builtin_bit_cast(bf16x8, v);
}
// pack two f32 -> (bf16(b)<<16)|bf16(a) by truncation, single v_perm
__device__ __forceinline__ unsigned pack_trunc2(float a, float b) {
    return __builtin_amdgcn_perm(__float_as_uint(b), __float_as_uint(a), 0x07060302u);
}
// Non-sinkable async global->LDS, 16 B/lane. HW uses wave-uniform LDS base + lane*16.
__device__ __forceinline__ void async_ld16(const void* g, void* lds) {
    __builtin_amdgcn_global_load_lds(
        (const __attribute__((address_space(1))) void*)g,
        (__attribute__((address_space(3))) void*)lds, 16, 0, 0);
}

// ---------------- Kernel 0: WbT[f][k] = bf16(W[k][f]) ----------------
__global__ __launch_bounds__(256) void wtrans_kernel(const float* __restrict__ W,
                                                     unsigned short* __restrict__ WbT) {
    int idx = blockIdx.x * 256 + threadIdx.x;   // 65536 elems
    int k = idx >> 8, f = idx & 255;
    WbT[f * 256 + k] = f2bf(W[idx]);
}

// ---------------- Kernel 1: PB = MFMA-B-fragment-packed (h@W+b); fused f1/f2 ----------------
// PB unit (jc, fg, lane l=(cl,q)): 8 bf16 = Wh[j = jc*32 + q*8 .. +7][f = fg*16+cl].
// Block b -> chunk jc = (b&7)*32 + (b>>3): chunk jc (split jc/32 = b%8) is written by
// XCD b%8 == the XCD that gat (s = blockIdx&7) will read it on -> PB stays XCD-local.
__global__ __launch_bounds__(256) void gemm1_kernel(const float* __restrict__ h,
                                                    const unsigned short* __restrict__ WbT,
                                                    const float* __restrict__ bias,
                                                    const float* __restrict__ av,
                                                    unsigned short* __restrict__ PBu,
                                                    float* __restrict__ f1p,
                                                    float* __restrict__ f2p) {
    __shared__ float Wh_s[256 * 33];   // [f][i-local], +1 pad
    __shared__ float red_s[2 * 8 * 32];
    int t = threadIdx.x;
    int l = t & 63, w = t >> 6;
    int jc = (blockIdx.x & 7) * 32 + (blockIdx.x >> 3);
    int i0 = jc * 32;
    int fbase = w * 64;
    int cl = l & 15, q = l >> 4;

    f32x4 acc[2][4] = {};
    const float* hA0 = h + (size_t)(i0 + cl) * FD;
    const float* hA1 = h + (size_t)(i0 + 16 + cl) * FD;

    #pragma unroll
    for (int ks = 0; ks < 8; ++ks) {
        int kk = ks * 32 + q * 8;
        union { unsigned short u[8]; bf16x8 v; } ua0, ua1;
        float4 x0 = *(const float4*)(hA0 + kk);
        float4 x1 = *(const float4*)(hA0 + kk + 4);
        float4 y0 = *(const float4*)(hA1 + kk);
        float4 y1 = *(const float4*)(hA1 + kk + 4);
        ua0.u[0]=f2bf(x0.x); ua0.u[1]=f2bf(x0.y); ua0.u[2]=f2bf(x0.z); ua0.u[3]=f2bf(x0.w);
        ua0.u[4]=f2bf(x1.x); ua0.u[5]=f2bf(x1.y); ua0.u[6]=f2bf(x1.z); ua0.u[7]=f2bf(x1.w);
        ua1.u[0]=f2bf(y0.x); ua1.u[1]=f2bf(y0.y); ua1.u[2]=f2bf(y0.z); ua1.u[3]=f2bf(y0.w);
        ua1.u[4]=f2bf(y1.x); ua1.u[5]=f2bf(y1.y); ua1.u[6]=f2bf(y1.z); ua1.u[7]=f2bf(y1.w);
        #pragma unroll
        for (int bg = 0; bg < 4; ++bg) {
            bf16x8 bF = ld_bf8(WbT + (fbase + bg * 16 + cl) * 256 + kk);
            acc[0][bg] = __builtin_amdgcn_mfma_f32_16x16x32_bf16(ua0.v, bF, acc[0][bg], 0, 0, 0);
            acc[1][bg] = __builtin_amdgcn_mfma_f32_16x16x32_bf16(ua1.v, bF, acc[1][bg], 0, 0, 0);
        }
    }

    // C layout: col = lane&15, row = (lane>>4)*4 + reg   [m89-verified]
    #pragma unroll
    for (int mt = 0; mt < 2; ++mt)
        #pragma unroll
        for (int bg = 0; bg < 4; ++bg)
            #pragma unroll
            for (int e = 0; e < 4; ++e) {
                int il = mt * 16 + q * 4 + e;
                int fl = fbase + bg * 16 + cl;
                Wh_s[fl * 33 + il] = acc[mt][bg][e] + bias[fl];
            }
    __syncthreads();
    {   // emit packed-B fragments for chunk jc
        size_t jcBase = (size_t)jc * 8192;   // 16 fg * 64 lanes * 8 elems
        #pragma unroll
        for (int u = 0; u < 4; ++u) {
            int fg = u * 4 + (t >> 6);
            int ll = t & 63;
            int c2 = ll & 15, q2 = ll >> 4;
            const float* src = &Wh_s[(fg * 16 + c2) * 33 + q2 * 8];
            union { unsigned short us[8]; uint4 v; } p;
            #pragma unroll
            for (int e = 0; e < 8; ++e) p.us[e] = f2bf(src[e]);
            *(uint4*)(PBu + jcBase + fg * 512 + ll * 8) = p.v;
        }
    }
    // fused f1/f2 partials: thread t -> i = t&31, f-chunk = t>>5 (32 f's)
    {
        int i = t & 31, fc = t >> 5;
        float s1 = 0.f, s2 = 0.f;
        #pragma unroll
        for (int fo = 0; fo < 32; ++fo) {
            int f = fc * 32 + fo;
            float wv = Wh_s[f * 33 + i];
            s1 += wv * av[f];
            s2 += wv * av[256 + f];
        }
        red_s[fc * 32 + i] = s1;
        red_s[256 + fc * 32 + i] = s2;
    }
    __syncthreads();
    if (t < 32) {
        float s = 0.f;
        #pragma unroll
        for (int fc = 0; fc < 8; ++fc) s += red_s[fc * 32 + t];
        f1p[i0 + t] = s * LOG2E;
    } else if (t < 64) {
        int i = t - 32;
        float s = 0.f;
        #pragma unroll
        for (int fc = 0; fc < 8; ++fc) s += red_s[256 + fc * 32 + i];
        f2p[i0 + i] = s * LOG2E;
    }
}

// ---------------- Kernel 2: megafused GAT — counted-vmcnt pipelined barrier loop ----------------
// Grid = 128 strips x SPLIT; block = 256 thr (4 waves), 64 rows x 1024 j, 16 waves/CU.
//
// Sync template (NEW vs prior __syncthreads version) — vmcnt ledger:
//   issue order per iter g: [step2] B(g+1) x4 async_ld  [step3b] adj(g+2) x8.
//   entry(g):   outstanding = B(g){4, oldest} + adj(g+1){8}  -> s_waitcnt vmcnt(8)
//               (drains own B(g) staging, KEEPS adj in flight across s_barrier);
//               g==NIT-1: outstanding = B{4} only -> vmcnt(0).
//   step3a(g):  outstanding = adj(g+1){8, oldest} + B(g+1){4} -> vmcnt(4)
//               (adj had a FULL iteration of latency cover); ballot -> mask_b[(g+1)&1];
//               reuse same 8 VGPRs for adj(g+2).
//   masks are wave-private (wave w writes/reads only rows w*16..+15) -> no lgkm drain at
//   barriers; f2_s is read-only after prologue (one lgkmcnt(0) there).
//   Raw s_barrier never drains vmcnt -> per-CU adj bytes stay in flight continuously.
__global__ __launch_bounds__(256, 4) void gat_kernel(const int* __restrict__ adj,
                                                     const unsigned short* __restrict__ PBu,
                                                     const float* __restrict__ f1p,
                                                     const float* __restrict__ f2p,
                                                     float* __restrict__ num,
                                                     float* __restrict__ den) {
    __shared__ __align__(16) unsigned short Bs[2][8192];       // 32 KB dbuf (16 KB/chunk)
    __shared__ unsigned mask_b[2][64];                         // 512 B dbuf (64 rows x 32 bits)
    __shared__ float f2_s[JSLICE];                             // 4 KB

    int t = threadIdx.x;
    int l = t & 63, w = t >> 6;
    int s = blockIdx.x & 7;              // j-split (XCD-pinned under round-robin)
    int strip = blockIdx.x >> 3;
    int i0b = strip * 64;                // block's 64 rows
    int j0 = s * JSLICE;
    int jw0 = j0 / 32;
    int cl = l & 15, q = l >> 4;

    // ---- prologue: f2 slice, B chunk 0 (async), adj chunk 0, masks for g=0, adj chunk 1 ----
    *(float4*)&f2_s[t * 4] = *(const float4*)(f2p + j0 + t * 4);

    const char* pbBase = (const char*)(PBu + (size_t)jw0 * 8192);
    #pragma unroll
    for (int k = 0; k < 4; ++k)
        async_ld16(pbBase + k * 4096 + t * 16, (char*)&Bs[0][0] + k * 4096 + t * 16);

    // wave w ballots its own 16 rows: ballot k covers rows w*16+2k,+2k+1 x 32 j
    const int* arow = adj + (size_t)(i0b + w * 16 + (l >> 5)) * NN + j0 + (l & 31);
    int a0 = arow[0 * 2 * NN], a1 = arow[1 * 2 * NN], a2 = arow[2 * 2 * NN], a3 = arow[3 * 2 * NN];
    int a4 = arow[4 * 2 * NN], a5 = arow[5 * 2 * NN], a6 = arow[6 * 2 * NN], a7 = arow[7 * 2 * NN];

    float f1v = f1p[i0b + w * 16 + cl];  // wave w owns rows i0b + w*16 .. +15

    asm volatile("s_waitcnt vmcnt(0)" ::: "memory");   // f2, B(0), adj(0), f1v all landed
    {
        unsigned long long b0 = __ballot(a0 > 0), b1 = __ballot(a1 > 0);
        unsigned long long b2 = __ballot(a2 > 0), b3 = __ballot(a3 > 0);
        unsigned long long b4 = __ballot(a4 > 0), b5 = __ballot(a5 > 0);
        unsigned long long b6 = __ballot(a6 > 0), b7 = __ballot(a7 > 0);
        if (l == 0) {
            *(uint2*)&mask_b[0][w * 16 + 0]  = make_uint2((unsigned)b0, (unsigned)(b0 >> 32));
            *(uint2*)&mask_b[0][w * 16 + 2]  = make_uint2((unsigned)b1, (unsigned)(b1 >> 32));
            *(uint2*)&mask_b[0][w * 16 + 4]  = make_uint2((unsigned)b2, (unsigned)(b2 >> 32));
            *(uint2*)&mask_b[0][w * 16 + 6]  = make_uint2((unsigned)b3, (unsigned)(b3 >> 32));
            *(uint2*)&mask_b[0][w * 16 + 8]  = make_uint2((unsigned)b4, (unsigned)(b4 >> 32));
            *(uint2*)&mask_b[0][w * 16 + 10] = make_uint2((unsigned)b5, (unsigned)(b5 >> 32));
            *(uint2*)&mask_b[0][w * 16 + 12] = make_uint2((unsigned)b6, (unsigned)(b6 >> 32));
            *(uint2*)&mask_b[0][w * 16 + 14] = make_uint2((unsigned)b7, (unsigned)(b7 >> 32));
        }
    }
    // issue adj chunk 1 (balloted inside iteration g=0, after a full iteration of cover)
    a0 = arow[0 * 2 * NN + 32]; a1 = arow[1 * 2 * NN + 32];
    a2 = arow[2 * 2 * NN + 32]; a3 = arow[3 * 2 * NN + 32];
    a4 = arow[4 * 2 * NN + 32]; a5 = arow[5 * 2 * NN + 32];
    a6 = arow[6 * 2 * NN + 32]; a7 = arow[7 * 2 * NN + 32];
    asm volatile("s_waitcnt lgkmcnt(0)" ::: "memory");  // f2_s (cross-wave) + mask writes done

    // all-ones B fragment (bf16 1.0 = 0x3F80) for the rowsum MFMA
    const bf16x8 onesB = __builtin_bit_cast(bf16x8,
        make_uint4(0x3F803F80u, 0x3F803F80u, 0x3F803F80u, 0x3F803F80u));

    f32x4 acc[16] = {};
    f32x4 accR = {};                     // rowsum accumulator

    #pragma unroll 1
    for (int g = 0; g < NIT; ++g) {
        __builtin_amdgcn_sched_barrier(0);
        if (g == NIT - 1) {
            asm volatile("s_waitcnt vmcnt(0)" ::: "memory");   // only B(g) outstanding
        } else {
            asm volatile("s_waitcnt vmcnt(8)" ::: "memory");   // drain B(g), keep adj(g+1)
        }
        __builtin_amdgcn_s_barrier();
        __builtin_amdgcn_sched_barrier(0);

        if (g + 1 < NIT) {
            // stage B(g+1) into the buffer last read at iteration g-1 (all waves past it)
            const char* src = pbBase + (size_t)(g + 1) * 16384;
            char* dst = (char*)&Bs[(g + 1) & 1][0];
            #pragma unroll
            for (int k = 0; k < 4; ++k)
                async_ld16(src + k * 4096 + t * 16, dst + k * 4096 + t * 16);
            // adj(g+1) {8, oldest} + B(g+1) {4} outstanding -> drain adj only
            asm volatile("s_waitcnt vmcnt(4)" ::: "memory");
            int nb = (g + 1) & 1;
            unsigned long long b0 = __ballot(a0 > 0), b1 = __ballot(a1 > 0);
            unsigned long long b2 = __ballot(a2 > 0), b3 = __ballot(a3 > 0);
            unsigned long long b4 = __ballot(a4 > 0), b5 = __ballot(a5 > 0);
            unsigned long long b6 = __ballot(a6 > 0), b7 = __ballot(a7 > 0);
            if (l == 0) {
                *(uint2*)&mask_b[nb][w * 16 + 0]  = make_uint2((unsigned)b0, (unsigned)(b0 >> 32));
                *(uint2*)&mask_b[nb][w * 16 + 2]  = make_uint2((unsigned)b1, (unsigned)(b1 >> 32));
                *(uint2*)&mask_b[nb][w * 16 + 4]  = make_uint2((unsigned)b2, (unsigned)(b2 >> 32));
                *(uint2*)&mask_b[nb][w * 16 + 6]  = make_uint2((unsigned)b3, (unsigned)(b3 >> 32));
                *(uint2*)&mask_b[nb][w * 16 + 8]  = make_uint2((unsigned)b4, (unsigned)(b4 >> 32));
                *(uint2*)&mask_b[nb][w * 16 + 10] = make_uint2((unsigned)b5, (unsigned)(b5 >> 32));
                *(uint2*)&mask_b[nb][w * 16 + 12] = make_uint2((unsigned)b6, (unsigned)(b6 >> 32));
                *(uint2*)&mask_b[nb][w * 16 + 14] = make_uint2((unsigned)b7, (unsigned)(b7 >> 32));
            }
            if (g + 2 < NIT) {   // reuse the same 8 VGPRs for the next adj batch
                int jo = (g + 2) * 32;
                a0 = arow[0 * 2 * NN + jo]; a1 = arow[1 * 2 * NN + jo];
                a2 = arow[2 * 2 * NN + jo]; a3 = arow[3 * 2 * NN + jo];
                a4 = arow[4 * 2 * NN + jo]; a5 = arow[5 * 2 * NN + jo];
                a6 = arow[6 * 2 * NN + jo]; a7 = arow[7 * 2 * NN + jo];
            }
        }

        // ---- compute chunk g (masks written last iteration; B staged last iteration) ----
        unsigned mw = mask_b[g & 1][w * 16 + cl];
        float4 F0 = *(const float4*)&f2_s[g * 32 + q * 8];
        float4 F1 = *(const float4*)&f2_s[g * 32 + q * 8 + 4];

        unsigned bits = mw >> (q * 8);
        float fe[8] = {F0.x, F0.y, F0.z, F0.w, F1.x, F1.y, F1.z, F1.w};
        float wv[8];
        #pragma unroll
        for (int e = 0; e < 8; ++e) {
            float sv = f1v + fe[e];
            sv = fmaxf(sv, 0.2f * sv);           // leaky_relu, pre-scaled by log2e
            float x = __builtin_amdgcn_exp2f(sv);
            x = (bits >> e) & 1 ? x : 0.f;
            wv[e] = x;
        }
        union { unsigned uu[4]; bf16x8 v; } af;
        af.uu[0] = pack_trunc2(wv[0], wv[1]);
        af.uu[1] = pack_trunc2(wv[2], wv[3]);
        af.uu[2] = pack_trunc2(wv[4], wv[5]);
        af.uu[3] = pack_trunc2(wv[6], wv[7]);

        const unsigned short* bu = &Bs[g & 1][0] + l * 8;
        #pragma unroll
        for (int fg = 0; fg < 16; ++fg) {
            bf16x8 B = ld_bf8(bu + fg * 512);
            acc[fg] = __builtin_amdgcn_mfma_f32_16x16x32_bf16(af.v, B, acc[fg], 0, 0, 0);
        }
        accR = __builtin_amdgcn_mfma_f32_16x16x32_bf16(af.v, onesB, accR, 0, 0, 0);
    }

    // denominator: accR C layout row = q*4+e, every col identical; cl==0 lanes write
    if (cl == 0) {
        #pragma unroll
        for (int e = 0; e < 4; ++e)
            den[(size_t)s * NN + i0b + w * 16 + q * 4 + e] = accR[e];
    }

    // partial numerator: C layout row r = q*4+e, col = fg*16+cl
    float* nrow = num + (size_t)s * NN * FD;
    #pragma unroll
    for (int e = 0; e < 4; ++e) {
        int r = i0b + w * 16 + q * 4 + e;
        #pragma unroll
        for (int fg = 0; fg < 16; ++fg)
            nrow[(size_t)r * FD + fg * 16 + cl] = acc[fg][e];
    }
}

// ---------------- Kernel 3: combine j-split partials ----------------
__global__ __launch_bounds__(256) void combine_kernel(const float* __restrict__ num,
                                                      const float* __restrict__ den,
                                                      float* __restrict__ out) {
    int idx = blockIdx.x * 256 + threadIdx.x;   // 2M elems; i uniform per block
    int i = idx >> 8;
    float nsum = 0.f, dsum = 0.f;
    #pragma unroll
    for (int s = 0; s < SPLIT; ++s) {
        nsum += num[(size_t)s * NN * FD + idx];
        dsum += den[(size_t)s * NN + i];
    }
    out[idx] = nsum / dsum;
}

extern "C" void kernel_launch(void* const* d_in, const int* in_sizes, int n_in,
                              void* d_out, int out_size, void* d_ws, size_t ws_size,
                              hipStream_t stream) {
    const float* h   = (const float*)d_in[0];
    const int*   adj = (const int*)d_in[1];
    const float* W   = (const float*)d_in[2];
    const float* b   = (const float*)d_in[3];
    const float* a   = (const float*)d_in[4];
    float* out = (float*)d_out;

    char* ws = (char*)d_ws;
    unsigned short* PBu = (unsigned short*)ws;                          // 4 MB packed Wh fragments
    unsigned short* WbT = (unsigned short*)(ws + (4u << 20));           // 128 KB
    float* f1p = (float*)(ws + (4u << 20) + (128u << 10));              // 32 KB
    float* f2p = f1p + NN;                                              // 32 KB
    float* den = f2p + NN;                                              // SPLIT*NN f32 = 256 KB
    float* num = (float*)(ws + (24u << 20));                            // SPLIT*8 MB = 64 MB

    wtrans_kernel<<<256, 256, 0, stream>>>(W, WbT);
    gemm1_kernel<<<256, 256, 0, stream>>>(h, WbT, b, a, PBu, f1p, f2p);
    gat_kernel<<<128 * SPLIT, 256, 0, stream>>>(adj, PBu, f1p, f2p, num, den);
    combine_kernel<<<NN * FD / 256, 256, 0, stream>>>(num, den, out);
}

// Round 2
// 428.846 us; speedup vs baseline: 1.0295x; 1.0295x over previous
//
#include <hip/hip_runtime.h>
#include <stdint.h>

#define NN 8192
#define FD 256
#define LOG2E 1.44269504088896340736f
#define SPLIT 8
#define JSLICE (NN / SPLIT)      // 1024 j per gat block
#define NIT (JSLICE / 32)        // 32 B-iterations of 32 j (16 KB B-chunk each)
#define NADJ (JSLICE / 64)       // 16 adj chunks of 64 j (one chunk = 2 B-iters)

typedef __attribute__((ext_vector_type(8))) __bf16 bf16x8;
typedef __attribute__((ext_vector_type(4))) float f32x4;

__device__ __forceinline__ unsigned short f2bf(float x) {
    unsigned u = __float_as_uint(x);
    u = u + 0x7fffu + ((u >> 16) & 1u);   // RNE; no NaNs in this problem
    return (unsigned short)(u >> 16);
}
__device__ __forceinline__ bf16x8 ld_bf8(const unsigned short* p) {
    uint4 v = *(const uint4*)p;
    return __builtin_bit_cast(bf16x8, v);
}
// pack two f32 -> (bf16(b)<<16)|bf16(a) by truncation, single v_perm
__device__ __forceinline__ unsigned pack_trunc2(float a, float b) {
    return __builtin_amdgcn_perm(__float_as_uint(b), __float_as_uint(a), 0x07060302u);
}
// Non-sinkable async global->LDS, 16 B/lane. HW uses wave-uniform LDS base + lane*16.
__device__ __forceinline__ void async_ld16(const void* g, void* lds) {
    __builtin_amdgcn_global_load_lds(
        (const __attribute__((address_space(1))) void*)g,
        (__attribute__((address_space(3))) void*)lds, 16, 0, 0);
}

// ---------------- Kernel 0: WbT[f][k] = bf16(W[k][f]) ----------------
__global__ __launch_bounds__(256) void wtrans_kernel(const float* __restrict__ W,
                                                     unsigned short* __restrict__ WbT) {
    int idx = blockIdx.x * 256 + threadIdx.x;   // 65536 elems
    int k = idx >> 8, f = idx & 255;
    WbT[f * 256 + k] = f2bf(W[idx]);
}

// ---------------- Kernel 1: PB = MFMA-B-fragment-packed (h@W+b); fused f1/f2 ----------------
// PB unit (jc, fg, lane l=(cl,q)): 8 bf16 = Wh[j = jc*32 + q*8 .. +7][f = fg*16+cl].
// Block b -> chunk jc = (b&7)*32 + (b>>3): chunk jc (split jc/32 = b%8) is written by
// XCD b%8 == the XCD that gat (s = blockIdx&7) will read it on -> PB stays XCD-local.
__global__ __launch_bounds__(256) void gemm1_kernel(const float* __restrict__ h,
                                                    const unsigned short* __restrict__ WbT,
                                                    const float* __restrict__ bias,
                                                    const float* __restrict__ av,
                                                    unsigned short* __restrict__ PBu,
                                                    float* __restrict__ f1p,
                                                    float* __restrict__ f2p) {
    __shared__ float Wh_s[256 * 33];   // [f][i-local], +1 pad
    __shared__ float red_s[2 * 8 * 32];
    int t = threadIdx.x;
    int l = t & 63, w = t >> 6;
    int jc = (blockIdx.x & 7) * 32 + (blockIdx.x >> 3);
    int i0 = jc * 32;
    int fbase = w * 64;
    int cl = l & 15, q = l >> 4;

    f32x4 acc[2][4] = {};
    const float* hA0 = h + (size_t)(i0 + cl) * FD;
    const float* hA1 = h + (size_t)(i0 + 16 + cl) * FD;

    #pragma unroll
    for (int ks = 0; ks < 8; ++ks) {
        int kk = ks * 32 + q * 8;
        union { unsigned short u[8]; bf16x8 v; } ua0, ua1;
        float4 x0 = *(const float4*)(hA0 + kk);
        float4 x1 = *(const float4*)(hA0 + kk + 4);
        float4 y0 = *(const float4*)(hA1 + kk);
        float4 y1 = *(const float4*)(hA1 + kk + 4);
        ua0.u[0]=f2bf(x0.x); ua0.u[1]=f2bf(x0.y); ua0.u[2]=f2bf(x0.z); ua0.u[3]=f2bf(x0.w);
        ua0.u[4]=f2bf(x1.x); ua0.u[5]=f2bf(x1.y); ua0.u[6]=f2bf(x1.z); ua0.u[7]=f2bf(x1.w);
        ua1.u[0]=f2bf(y0.x); ua1.u[1]=f2bf(y0.y); ua1.u[2]=f2bf(y0.z); ua1.u[3]=f2bf(y0.w);
        ua1.u[4]=f2bf(y1.x); ua1.u[5]=f2bf(y1.y); ua1.u[6]=f2bf(y1.z); ua1.u[7]=f2bf(y1.w);
        #pragma unroll
        for (int bg = 0; bg < 4; ++bg) {
            bf16x8 bF = ld_bf8(WbT + (fbase + bg * 16 + cl) * 256 + kk);
            acc[0][bg] = __builtin_amdgcn_mfma_f32_16x16x32_bf16(ua0.v, bF, acc[0][bg], 0, 0, 0);
            acc[1][bg] = __builtin_amdgcn_mfma_f32_16x16x32_bf16(ua1.v, bF, acc[1][bg], 0, 0, 0);
        }
    }

    // C layout: col = lane&15, row = (lane>>4)*4 + reg   [m89-verified]
    #pragma unroll
    for (int mt = 0; mt < 2; ++mt)
        #pragma unroll
        for (int bg = 0; bg < 4; ++bg)
            #pragma unroll
            for (int e = 0; e < 4; ++e) {
                int il = mt * 16 + q * 4 + e;
                int fl = fbase + bg * 16 + cl;
                Wh_s[fl * 33 + il] = acc[mt][bg][e] + bias[fl];
            }
    __syncthreads();
    {   // emit packed-B fragments for chunk jc
        size_t jcBase = (size_t)jc * 8192;   // 16 fg * 64 lanes * 8 elems
        #pragma unroll
        for (int u = 0; u < 4; ++u) {
            int fg = u * 4 + (t >> 6);
            int ll = t & 63;
            int c2 = ll & 15, q2 = ll >> 4;
            const float* src = &Wh_s[(fg * 16 + c2) * 33 + q2 * 8];
            union { unsigned short us[8]; uint4 v; } p;
            #pragma unroll
            for (int e = 0; e < 8; ++e) p.us[e] = f2bf(src[e]);
            *(uint4*)(PBu + jcBase + fg * 512 + ll * 8) = p.v;
        }
    }
    // fused f1/f2 partials: thread t -> i = t&31, f-chunk = t>>5 (32 f's)
    {
        int i = t & 31, fc = t >> 5;
        float s1 = 0.f, s2 = 0.f;
        #pragma unroll
        for (int fo = 0; fo < 32; ++fo) {
            int f = fc * 32 + fo;
            float wv = Wh_s[f * 33 + i];
            s1 += wv * av[f];
            s2 += wv * av[256 + f];
        }
        red_s[fc * 32 + i] = s1;
        red_s[256 + fc * 32 + i] = s2;
    }
    __syncthreads();
    if (t < 32) {
        float s = 0.f;
        #pragma unroll
        for (int fc = 0; fc < 8; ++fc) s += red_s[fc * 32 + t];
        f1p[i0 + t] = s * LOG2E;
    } else if (t < 64) {
        int i = t - 32;
        float s = 0.f;
        #pragma unroll
        for (int fc = 0; fc < 8; ++fc) s += red_s[256 + fc * 32 + i];
        f2p[i0 + i] = s * LOG2E;
    }
}

// ---------------- Kernel 2: megafused GAT — wide contiguous adj reads ----------------
// Grid = 128 strips x SPLIT; block = 256 thr (4 waves), 64 rows x 1024 j, 16 waves/CU.
// adj is read in 64-j chunks via dwordx4 (one load = 4 rows x 64 j; 256 B contiguous per
// row — 2x the DRAM burst of the old 32-j scalar path, 4x fewer load insts).
// Mask assembly: per-lane 4-bit nibble -> OR-combine across 8-lane groups (3 shfl_xor)
// -> 32-bit j-ordered row-mask words into a 4-deep LDS ring. Masks stay wave-private.
// Schedule: even B-iter body issues adj chunk (g/2+1); entry __syncthreads of the odd
// iter drains them (>=1500 cyc cover >> ~900 cyc HBM latency); odd body ballots.
__global__ __launch_bounds__(256, 4) void gat_kernel(const int* __restrict__ adj,
                                                     const unsigned short* __restrict__ PBu,
                                                     const float* __restrict__ f1p,
                                                     const float* __restrict__ f2p,
                                                     float* __restrict__ num,
                                                     float* __restrict__ den) {
    __shared__ __align__(16) unsigned short Bs[2][8192];       // 32 KB dbuf (16 KB/chunk)
    __shared__ unsigned mask_b[4][64];                         // 1 KB ring (4 B-iters deep)
    __shared__ float f2_s[JSLICE];                             // 4 KB

    int t = threadIdx.x;
    int l = t & 63, w = t >> 6;
    int s = blockIdx.x & 7;              // j-split (XCD-pinned under round-robin)
    int strip = blockIdx.x >> 3;
    int i0b = strip * 64;                // block's 64 rows
    int j0 = s * JSLICE;
    int jw0 = j0 / 32;
    int cl = l & 15, q = l >> 4;

    // ---- prologue: f2 slice, B chunk 0 (async), adj chunk 0 (wide) ----
    *(float4*)&f2_s[t * 4] = *(const float4*)(f2p + j0 + t * 4);

    const char* pbBase = (const char*)(PBu + (size_t)jw0 * 8192);
    #pragma unroll
    for (int k = 0; k < 4; ++k)
        async_ld16(pbBase + k * 4096 + t * 16, (char*)&Bs[0][0] + k * 4096 + t * 16);

    // wide-adj base: lane l covers row i0b + w*16 + ld*4 + (l>>4), j = j0 + (l&15)*4 .. +3
    const int* abase = adj + (size_t)(i0b + w * 16 + (l >> 4)) * NN + j0 + (l & 15) * 4;
    int4 A0 = *(const int4*)(abase + 0 * 4 * NN);
    int4 A1 = *(const int4*)(abase + 1 * 4 * NN);
    int4 A2 = *(const int4*)(abase + 2 * 4 * NN);
    int4 A3 = *(const int4*)(abase + 3 * 4 * NN);

    float f1v = f1p[i0b + w * 16 + cl];  // wave w owns rows i0b + w*16 .. +15

    __syncthreads();   // drains f2, B(0), adj chunk 0, f1v; orders f2_s across waves

    // ballot adj chunk 0 -> mask slots 0,1 (wave-private rows)
    {
        int word = (l >> 3) & 1;           // which 32-j word of this row
        int sh = 4 * (l & 7);              // nibble position within word
        int rsub = l >> 4;                 // row-within-load-group
        #pragma unroll
        for (int ld = 0; ld < 4; ++ld) {
            int4 A = ld == 0 ? A0 : ld == 1 ? A1 : ld == 2 ? A2 : A3;
            unsigned n = (unsigned)(A.x > 0) | ((unsigned)(A.y > 0) << 1)
                       | ((unsigned)(A.z > 0) << 2) | ((unsigned)(A.w > 0) << 3);
            unsigned v = n << sh;
            v |= __shfl_xor(v, 1);
            v |= __shfl_xor(v, 2);
            v |= __shfl_xor(v, 4);
            if ((l & 7) == 0)
                mask_b[word][w * 16 + ld * 4 + rsub] = v;
        }
    }

    // all-ones B fragment (bf16 1.0 = 0x3F80) for the rowsum MFMA
    const bf16x8 onesB = __builtin_bit_cast(bf16x8,
        make_uint4(0x3F803F80u, 0x3F803F80u, 0x3F803F80u, 0x3F803F80u));

    f32x4 acc[16] = {};
    f32x4 accR = {};                     // rowsum accumulator

    #pragma unroll 1
    for (int g = 0; g < NIT; ++g) {
        __syncthreads();   // drains B(g) staging + adj loads issued at body g-1

        if (g + 1 < NIT) {
            // stage B(g+1) into the buffer last read at iteration g-1
            const char* src = pbBase + (size_t)(g + 1) * 16384;
            char* dst = (char*)&Bs[(g + 1) & 1][0];
            #pragma unroll
            for (int k = 0; k < 4; ++k)
                async_ld16(src + k * 4096 + t * 16, dst + k * 4096 + t * 16);
        }

        if ((g & 1) == 0) {
            // even body: issue adj chunk (g/2 + 1) wide loads (drained by next entry sync)
            int c1 = g / 2 + 1;
            if (c1 < NADJ) {
                int jo = c1 * 64;
                A0 = *(const int4*)(abase + 0 * 4 * NN + jo);
                A1 = *(const int4*)(abase + 1 * 4 * NN + jo);
                A2 = *(const int4*)(abase + 2 * 4 * NN + jo);
                A3 = *(const int4*)(abase + 3 * 4 * NN + jo);
            }
        } else {
            // odd body: ballot adj chunk (g+1)/2 -> mask slots (g+1)&3, (g+2)&3
            int c1 = (g + 1) / 2;
            if (c1 < NADJ) {
                int word = (l >> 3) & 1;
                int slot = (g + 1 + word) & 3;
                int sh = 4 * (l & 7);
                int rsub = l >> 4;
                #pragma unroll
                for (int ld = 0; ld < 4; ++ld) {
                    int4 A = ld == 0 ? A0 : ld == 1 ? A1 : ld == 2 ? A2 : A3;
                    unsigned n = (unsigned)(A.x > 0) | ((unsigned)(A.y > 0) << 1)
                               | ((unsigned)(A.z > 0) << 2) | ((unsigned)(A.w > 0) << 3);
                    unsigned v = n << sh;
                    v |= __shfl_xor(v, 1);
                    v |= __shfl_xor(v, 2);
                    v |= __shfl_xor(v, 4);
                    if ((l & 7) == 0)
                        mask_b[slot][w * 16 + ld * 4 + rsub] = v;
                }
            }
        }

        // ---- compute chunk g (masks written >=1 iter ago, same wave; B staged last iter) ----
        unsigned mw = mask_b[g & 3][w * 16 + cl];
        float4 F0 = *(const float4*)&f2_s[g * 32 + q * 8];
        float4 F1 = *(const float4*)&f2_s[g * 32 + q * 8 + 4];

        unsigned bits = mw >> (q * 8);
        float fe[8] = {F0.x, F0.y, F0.z, F0.w, F1.x, F1.y, F1.z, F1.w};
        float wv[8];
        #pragma unroll
        for (int e = 0; e < 8; ++e) {
            float sv = f1v + fe[e];
            sv = fmaxf(sv, 0.2f * sv);           // leaky_relu, pre-scaled by log2e
            float x = __builtin_amdgcn_exp2f(sv);
            x = (bits >> e) & 1 ? x : 0.f;
            wv[e] = x;
        }
        union { unsigned uu[4]; bf16x8 v; } af;
        af.uu[0] = pack_trunc2(wv[0], wv[1]);
        af.uu[1] = pack_trunc2(wv[2], wv[3]);
        af.uu[2] = pack_trunc2(wv[4], wv[5]);
        af.uu[3] = pack_trunc2(wv[6], wv[7]);

        const unsigned short* bu = &Bs[g & 1][0] + l * 8;
        #pragma unroll
        for (int fg = 0; fg < 16; ++fg) {
            bf16x8 B = ld_bf8(bu + fg * 512);
            acc[fg] = __builtin_amdgcn_mfma_f32_16x16x32_bf16(af.v, B, acc[fg], 0, 0, 0);
        }
        accR = __builtin_amdgcn_mfma_f32_16x16x32_bf16(af.v, onesB, accR, 0, 0, 0);
    }

    // denominator: accR C layout row = q*4+e, every col identical; cl==0 lanes write
    if (cl == 0) {
        #pragma unroll
        for (int e = 0; e < 4; ++e)
            den[(size_t)s * NN + i0b + w * 16 + q * 4 + e] = accR[e];
    }

    // partial numerator: C layout row r = q*4+e, col = fg*16+cl
    float* nrow = num + (size_t)s * NN * FD;
    #pragma unroll
    for (int e = 0; e < 4; ++e) {
        int r = i0b + w * 16 + q * 4 + e;
        #pragma unroll
        for (int fg = 0; fg < 16; ++fg)
            nrow[(size_t)r * FD + fg * 16 + cl] = acc[fg][e];
    }
}

// ---------------- Kernel 3: combine j-split partials ----------------
__global__ __launch_bounds__(256) void combine_kernel(const float* __restrict__ num,
                                                      const float* __restrict__ den,
                                                      float* __restrict__ out) {
    int idx = blockIdx.x * 256 + threadIdx.x;   // 2M elems; i uniform per block
    int i = idx >> 8;
    float nsum = 0.f, dsum = 0.f;
    #pragma unroll
    for (int s = 0; s < SPLIT; ++s) {
        nsum += num[(size_t)s * NN * FD + idx];
        dsum += den[(size_t)s * NN + i];
    }
    out[idx] = nsum / dsum;
}

extern "C" void kernel_launch(void* const* d_in, const int* in_sizes, int n_in,
                              void* d_out, int out_size, void* d_ws, size_t ws_size,
                              hipStream_t stream) {
    const float* h   = (const float*)d_in[0];
    const int*   adj = (const int*)d_in[1];
    const float* W   = (const float*)d_in[2];
    const float* b   = (const float*)d_in[3];
    const float* a   = (const float*)d_in[4];
    float* out = (float*)d_out;

    char* ws = (char*)d_ws;
    unsigned short* PBu = (unsigned short*)ws;                          // 4 MB packed Wh fragments
    unsigned short* WbT = (unsigned short*)(ws + (4u << 20));           // 128 KB
    float* f1p = (float*)(ws + (4u << 20) + (128u << 10));              // 32 KB
    float* f2p = f1p + NN;                                              // 32 KB
    float* den = f2p + NN;                                              // SPLIT*NN f32 = 256 KB
    float* num = (float*)(ws + (24u << 20));                            // SPLIT*8 MB = 64 MB

    wtrans_kernel<<<256, 256, 0, stream>>>(W, WbT);
    gemm1_kernel<<<256, 256, 0, stream>>>(h, WbT, b, a, PBu, f1p, f2p);
    gat_kernel<<<128 * SPLIT, 256, 0, stream>>>(adj, PBu, f1p, f2p, num, den);
    combine_kernel<<<NN * FD / 256, 256, 0, stream>>>(num, den, out);
}

// Round 4
// 419.383 us; speedup vs baseline: 1.0528x; 1.0226x over previous
//
#include <hip/hip_runtime.h>
#include <stdint.h>

#define NN 8192
#define FD 256
#define LOG2E 1.44269504088896340736f
#define SPLIT 4
#define JSLICE (NN / SPLIT)      // 2048 j per gat block
#define NIT (JSLICE / 32)        // 64 B-iterations of 32 j (16 KB B-chunk each)
#define NADJ (JSLICE / 64)       // 32 adj chunks of 64 j (one chunk = 2 B-iters)

typedef __attribute__((ext_vector_type(8))) __bf16 bf16x8;
typedef __attribute__((ext_vector_type(4))) float f32x4;
typedef __attribute__((ext_vector_type(4))) int i32x4;

__device__ __forceinline__ unsigned short f2bf(float x) {
    unsigned u = __float_as_uint(x);
    u = u + 0x7fffu + ((u >> 16) & 1u);   // RNE; no NaNs in this problem
    return (unsigned short)(u >> 16);
}
__device__ __forceinline__ bf16x8 ld_bf8(const unsigned short* p) {
    uint4 v = *(const uint4*)p;
    return __builtin_bit_cast(bf16x8, v);
}
// pack two f32 -> (bf16(b)<<16)|bf16(a) by truncation, single v_perm
__device__ __forceinline__ unsigned pack_trunc2(float a, float b) {
    return __builtin_amdgcn_perm(__float_as_uint(b), __float_as_uint(a), 0x07060302u);
}
// Non-sinkable async global->LDS, 16 B/lane. HW uses wave-uniform LDS base + lane*16.
__device__ __forceinline__ void async_ld16(const void* g, void* lds) {
    __builtin_amdgcn_global_load_lds(
        (const __attribute__((address_space(1))) void*)g,
        (__attribute__((address_space(3))) void*)lds, 16, 0, 0);
}
// Non-temporal 16B load (native clang vector type — HIP int4 struct is rejected
// by __builtin_nontemporal_load). adj streams 256 MB once; keep it out of L2 so
// the XCD-local PB slice stays L2-resident.
__device__ __forceinline__ i32x4 ld_nt_i4(const int* p) {
    return __builtin_nontemporal_load((const i32x4*)p);
}

// ---------------- Kernel 0: WbT[f][k] = bf16(W[k][f]) ----------------
__global__ __launch_bounds__(256) void wtrans_kernel(const float* __restrict__ W,
                                                     unsigned short* __restrict__ WbT) {
    int idx = blockIdx.x * 256 + threadIdx.x;   // 65536 elems
    int k = idx >> 8, f = idx & 255;
    WbT[f * 256 + k] = f2bf(W[idx]);
}

// ---------------- Kernel 1: PB = MFMA-B-fragment-packed (h@W+b); fused f1/f2 ----------------
// PB unit (jc, fg, lane l=(cl,q)): 8 bf16 = Wh[j = jc*32 + q*8 .. +7][f = fg*16+cl].
__global__ __launch_bounds__(256) void gemm1_kernel(const float* __restrict__ h,
                                                    const unsigned short* __restrict__ WbT,
                                                    const float* __restrict__ bias,
                                                    const float* __restrict__ av,
                                                    unsigned short* __restrict__ PBu,
                                                    float* __restrict__ f1p,
                                                    float* __restrict__ f2p) {
    __shared__ float Wh_s[256 * 33];   // [f][i-local], +1 pad
    __shared__ float red_s[2 * 8 * 32];
    int t = threadIdx.x;
    int l = t & 63, w = t >> 6;
    int jc = (blockIdx.x & 7) * 32 + (blockIdx.x >> 3);
    int i0 = jc * 32;
    int fbase = w * 64;
    int cl = l & 15, q = l >> 4;

    f32x4 acc[2][4] = {};
    const float* hA0 = h + (size_t)(i0 + cl) * FD;
    const float* hA1 = h + (size_t)(i0 + 16 + cl) * FD;

    #pragma unroll
    for (int ks = 0; ks < 8; ++ks) {
        int kk = ks * 32 + q * 8;
        union { unsigned short u[8]; bf16x8 v; } ua0, ua1;
        float4 x0 = *(const float4*)(hA0 + kk);
        float4 x1 = *(const float4*)(hA0 + kk + 4);
        float4 y0 = *(const float4*)(hA1 + kk);
        float4 y1 = *(const float4*)(hA1 + kk + 4);
        ua0.u[0]=f2bf(x0.x); ua0.u[1]=f2bf(x0.y); ua0.u[2]=f2bf(x0.z); ua0.u[3]=f2bf(x0.w);
        ua0.u[4]=f2bf(x1.x); ua0.u[5]=f2bf(x1.y); ua0.u[6]=f2bf(x1.z); ua0.u[7]=f2bf(x1.w);
        ua1.u[0]=f2bf(y0.x); ua1.u[1]=f2bf(y0.y); ua1.u[2]=f2bf(y0.z); ua1.u[3]=f2bf(y0.w);
        ua1.u[4]=f2bf(y1.x); ua1.u[5]=f2bf(y1.y); ua1.u[6]=f2bf(y1.z); ua1.u[7]=f2bf(y1.w);
        #pragma unroll
        for (int bg = 0; bg < 4; ++bg) {
            bf16x8 bF = ld_bf8(WbT + (fbase + bg * 16 + cl) * 256 + kk);
            acc[0][bg] = __builtin_amdgcn_mfma_f32_16x16x32_bf16(ua0.v, bF, acc[0][bg], 0, 0, 0);
            acc[1][bg] = __builtin_amdgcn_mfma_f32_16x16x32_bf16(ua1.v, bF, acc[1][bg], 0, 0, 0);
        }
    }

    // C layout: col = lane&15, row = (lane>>4)*4 + reg   [m89-verified]
    #pragma unroll
    for (int mt = 0; mt < 2; ++mt)
        #pragma unroll
        for (int bg = 0; bg < 4; ++bg)
            #pragma unroll
            for (int e = 0; e < 4; ++e) {
                int il = mt * 16 + q * 4 + e;
                int fl = fbase + bg * 16 + cl;
                Wh_s[fl * 33 + il] = acc[mt][bg][e] + bias[fl];
            }
    __syncthreads();
    {   // emit packed-B fragments for chunk jc
        size_t jcBase = (size_t)jc * 8192;   // 16 fg * 64 lanes * 8 elems
        #pragma unroll
        for (int u = 0; u < 4; ++u) {
            int fg = u * 4 + (t >> 6);
            int ll = t & 63;
            int c2 = ll & 15, q2 = ll >> 4;
            const float* src = &Wh_s[(fg * 16 + c2) * 33 + q2 * 8];
            union { unsigned short us[8]; uint4 v; } p;
            #pragma unroll
            for (int e = 0; e < 8; ++e) p.us[e] = f2bf(src[e]);
            *(uint4*)(PBu + jcBase + fg * 512 + ll * 8) = p.v;
        }
    }
    // fused f1/f2 partials: thread t -> i = t&31, f-chunk = t>>5 (32 f's)
    {
        int i = t & 31, fc = t >> 5;
        float s1 = 0.f, s2 = 0.f;
        #pragma unroll
        for (int fo = 0; fo < 32; ++fo) {
            int f = fc * 32 + fo;
            float wv = Wh_s[f * 33 + i];
            s1 += wv * av[f];
            s2 += wv * av[256 + f];
        }
        red_s[fc * 32 + i] = s1;
        red_s[256 + fc * 32 + i] = s2;
    }
    __syncthreads();
    if (t < 32) {
        float s = 0.f;
        #pragma unroll
        for (int fc = 0; fc < 8; ++fc) s += red_s[fc * 32 + t];
        f1p[i0 + t] = s * LOG2E;
    } else if (t < 64) {
        int i = t - 32;
        float s = 0.f;
        #pragma unroll
        for (int fc = 0; fc < 8; ++fc) s += red_s[256 + fc * 32 + i];
        f2p[i0 + i] = s * LOG2E;
    }
}

// ---------------- Kernel 2: megafused GAT — SPLIT=4, wide nt adj reads ----------------
// Grid = 128 strips x SPLIT(=4); block = 256 thr (4 waves), 64 rows x 2048 j, 8 waves/CU.
// adj read in 64-j chunks via nontemporal dwordx4 (4 rows x 64 j per load; 256 B
// contiguous per row; L2-bypass keeps XCD-local PB slice resident).
// Mask assembly: per-lane 4-bit nibble -> OR across 8-lane groups (3 shfl_xor) -> 32-bit
// row-mask words into a 4-deep wave-private LDS ring.
// Schedule: even B-iter body issues adj chunk (g/2+1); next entry __syncthreads drains
// (full-iteration cover >> HBM latency); odd body ballots.
__global__ __launch_bounds__(256, 4) void gat_kernel(const int* __restrict__ adj,
                                                     const unsigned short* __restrict__ PBu,
                                                     const float* __restrict__ f1p,
                                                     const float* __restrict__ f2p,
                                                     float* __restrict__ num,
                                                     float* __restrict__ den) {
    __shared__ __align__(16) unsigned short Bs[2][8192];       // 32 KB dbuf (16 KB/chunk)
    __shared__ unsigned mask_b[4][64];                         // 1 KB ring (4 B-iters deep)
    __shared__ float f2_s[JSLICE];                             // 8 KB

    int t = threadIdx.x;
    int l = t & 63, w = t >> 6;
    int s = blockIdx.x & (SPLIT - 1);    // j-split
    int strip = blockIdx.x / SPLIT;
    int i0b = strip * 64;                // block's 64 rows
    int j0 = s * JSLICE;
    int jw0 = j0 / 32;
    int cl = l & 15, q = l >> 4;

    // ---- prologue: f2 slice (2048 floats), B chunk 0 (async), adj chunk 0 (wide) ----
    #pragma unroll
    for (int k = 0; k < JSLICE / 1024; ++k)
        *(float4*)&f2_s[k * 1024 + t * 4] = *(const float4*)(f2p + j0 + k * 1024 + t * 4);

    const char* pbBase = (const char*)(PBu + (size_t)jw0 * 8192);
    #pragma unroll
    for (int k = 0; k < 4; ++k)
        async_ld16(pbBase + k * 4096 + t * 16, (char*)&Bs[0][0] + k * 4096 + t * 16);

    // wide-adj base: lane l covers row i0b + w*16 + ld*4 + (l>>4), j = j0 + (l&15)*4 .. +3
    const int* abase = adj + (size_t)(i0b + w * 16 + (l >> 4)) * NN + j0 + (l & 15) * 4;
    i32x4 A0 = ld_nt_i4(abase + 0 * 4 * NN);
    i32x4 A1 = ld_nt_i4(abase + 1 * 4 * NN);
    i32x4 A2 = ld_nt_i4(abase + 2 * 4 * NN);
    i32x4 A3 = ld_nt_i4(abase + 3 * 4 * NN);

    float f1v = f1p[i0b + w * 16 + cl];  // wave w owns rows i0b + w*16 .. +15

    __syncthreads();   // drains f2, B(0), adj chunk 0, f1v; orders f2_s across waves

    // ballot adj chunk 0 -> mask slots 0,1 (wave-private rows)
    {
        int word = (l >> 3) & 1;           // which 32-j word of this row
        int sh = 4 * (l & 7);              // nibble position within word
        int rsub = l >> 4;                 // row-within-load-group
        #pragma unroll
        for (int ld = 0; ld < 4; ++ld) {
            i32x4 A = ld == 0 ? A0 : ld == 1 ? A1 : ld == 2 ? A2 : A3;
            unsigned n = (unsigned)(A[0] > 0) | ((unsigned)(A[1] > 0) << 1)
                       | ((unsigned)(A[2] > 0) << 2) | ((unsigned)(A[3] > 0) << 3);
            unsigned v = n << sh;
            v |= __shfl_xor(v, 1);
            v |= __shfl_xor(v, 2);
            v |= __shfl_xor(v, 4);
            if ((l & 7) == 0)
                mask_b[word][w * 16 + ld * 4 + rsub] = v;
        }
    }

    // all-ones B fragment (bf16 1.0 = 0x3F80) for the rowsum MFMA
    const bf16x8 onesB = __builtin_bit_cast(bf16x8,
        make_uint4(0x3F803F80u, 0x3F803F80u, 0x3F803F80u, 0x3F803F80u));

    f32x4 acc[16] = {};
    f32x4 accR = {};                     // rowsum accumulator

    #pragma unroll 1
    for (int g = 0; g < NIT; ++g) {
        __syncthreads();   // drains B(g) staging + adj loads issued at body g-1

        if (g + 1 < NIT) {
            // stage B(g+1) into the buffer last read at iteration g-1
            const char* src = pbBase + (size_t)(g + 1) * 16384;
            char* dst = (char*)&Bs[(g + 1) & 1][0];
            #pragma unroll
            for (int k = 0; k < 4; ++k)
                async_ld16(src + k * 4096 + t * 16, dst + k * 4096 + t * 16);
        }

        if ((g & 1) == 0) {
            // even body: issue adj chunk (g/2 + 1) wide loads (drained by next entry sync)
            int c1 = g / 2 + 1;
            if (c1 < NADJ) {
                int jo = c1 * 64;
                A0 = ld_nt_i4(abase + 0 * 4 * NN + jo);
                A1 = ld_nt_i4(abase + 1 * 4 * NN + jo);
                A2 = ld_nt_i4(abase + 2 * 4 * NN + jo);
                A3 = ld_nt_i4(abase + 3 * 4 * NN + jo);
            }
        } else {
            // odd body: ballot adj chunk (g+1)/2 -> mask slots (g+1)&3, (g+2)&3
            int c1 = (g + 1) / 2;
            if (c1 < NADJ) {
                int word = (l >> 3) & 1;
                int slot = (g + 1 + word) & 3;
                int sh = 4 * (l & 7);
                int rsub = l >> 4;
                #pragma unroll
                for (int ld = 0; ld < 4; ++ld) {
                    i32x4 A = ld == 0 ? A0 : ld == 1 ? A1 : ld == 2 ? A2 : A3;
                    unsigned n = (unsigned)(A[0] > 0) | ((unsigned)(A[1] > 0) << 1)
                               | ((unsigned)(A[2] > 0) << 2) | ((unsigned)(A[3] > 0) << 3);
                    unsigned v = n << sh;
                    v |= __shfl_xor(v, 1);
                    v |= __shfl_xor(v, 2);
                    v |= __shfl_xor(v, 4);
                    if ((l & 7) == 0)
                        mask_b[slot][w * 16 + ld * 4 + rsub] = v;
                }
            }
        }

        // ---- compute chunk g (masks written >=1 iter ago, same wave; B staged last iter) ----
        unsigned mw = mask_b[g & 3][w * 16 + cl];
        float4 F0 = *(const float4*)&f2_s[g * 32 + q * 8];
        float4 F1 = *(const float4*)&f2_s[g * 32 + q * 8 + 4];

        unsigned bits = mw >> (q * 8);
        float fe[8] = {F0.x, F0.y, F0.z, F0.w, F1.x, F1.y, F1.z, F1.w};
        float wv[8];
        #pragma unroll
        for (int e = 0; e < 8; ++e) {
            float sv = f1v + fe[e];
            sv = fmaxf(sv, 0.2f * sv);           // leaky_relu, pre-scaled by log2e
            float x = __builtin_amdgcn_exp2f(sv);
            x = (bits >> e) & 1 ? x : 0.f;
            wv[e] = x;
        }
        union { unsigned uu[4]; bf16x8 v; } af;
        af.uu[0] = pack_trunc2(wv[0], wv[1]);
        af.uu[1] = pack_trunc2(wv[2], wv[3]);
        af.uu[2] = pack_trunc2(wv[4], wv[5]);
        af.uu[3] = pack_trunc2(wv[6], wv[7]);

        const unsigned short* bu = &Bs[g & 1][0] + l * 8;
        #pragma unroll
        for (int fg = 0; fg < 16; ++fg) {
            bf16x8 B = ld_bf8(bu + fg * 512);
            acc[fg] = __builtin_amdgcn_mfma_f32_16x16x32_bf16(af.v, B, acc[fg], 0, 0, 0);
        }
        accR = __builtin_amdgcn_mfma_f32_16x16x32_bf16(af.v, onesB, accR, 0, 0, 0);
    }

    // denominator: accR C layout row = q*4+e, every col identical; cl==0 lanes write
    if (cl == 0) {
        #pragma unroll
        for (int e = 0; e < 4; ++e)
            den[(size_t)s * NN + i0b + w * 16 + q * 4 + e] = accR[e];
    }

    // partial numerator: C layout row r = q*4+e, col = fg*16+cl
    float* nrow = num + (size_t)s * NN * FD;
    #pragma unroll
    for (int e = 0; e < 4; ++e) {
        int r = i0b + w * 16 + q * 4 + e;
        #pragma unroll
        for (int fg = 0; fg < 16; ++fg)
            nrow[(size_t)r * FD + fg * 16 + cl] = acc[fg][e];
    }
}

// ---------------- Kernel 3: combine j-split partials ----------------
__global__ __launch_bounds__(256) void combine_kernel(const float* __restrict__ num,
                                                      const float* __restrict__ den,
                                                      float* __restrict__ out) {
    int idx = blockIdx.x * 256 + threadIdx.x;   // 2M elems; i uniform per block
    int i = idx >> 8;
    float nsum = 0.f, dsum = 0.f;
    #pragma unroll
    for (int s = 0; s < SPLIT; ++s) {
        nsum += num[(size_t)s * NN * FD + idx];
        dsum += den[(size_t)s * NN + i];
    }
    out[idx] = nsum / dsum;
}

extern "C" void kernel_launch(void* const* d_in, const int* in_sizes, int n_in,
                              void* d_out, int out_size, void* d_ws, size_t ws_size,
                              hipStream_t stream) {
    const float* h   = (const float*)d_in[0];
    const int*   adj = (const int*)d_in[1];
    const float* W   = (const float*)d_in[2];
    const float* b   = (const float*)d_in[3];
    const float* a   = (const float*)d_in[4];
    float* out = (float*)d_out;

    char* ws = (char*)d_ws;
    unsigned short* PBu = (unsigned short*)ws;                          // 4 MB packed Wh fragments
    unsigned short* WbT = (unsigned short*)(ws + (4u << 20));           // 128 KB
    float* f1p = (float*)(ws + (4u << 20) + (128u << 10));              // 32 KB
    float* f2p = f1p + NN;                                              // 32 KB
    float* den = f2p + NN;                                              // SPLIT*NN f32 = 128 KB
    float* num = (float*)(ws + (24u << 20));                            // SPLIT*8 MB = 32 MB

    wtrans_kernel<<<256, 256, 0, stream>>>(W, WbT);
    gemm1_kernel<<<256, 256, 0, stream>>>(h, WbT, b, a, PBu, f1p, f2p);
    gat_kernel<<<128 * SPLIT, 256, 0, stream>>>(adj, PBu, f1p, f2p, num, den);
    combine_kernel<<<NN * FD / 256, 256, 0, stream>>>(num, den, out);
}